// Round 10
// baseline (444.446 us; speedup 1.0000x reference)
//
#include <hip/hip_runtime.h>

#pragma clang diagnostic ignored "-Wregister"
#pragma clang diagnostic ignored "-Wdeprecated-register"

#define HID 128
#define EMB 64
#define VOCAB 120000

__device__ __forceinline__ float fast_tanh(float x) {   // 1 - 2/(exp(2x)+1)
    float e = __expf(2.f * x);
    return 1.f - __fdividef(2.f, e + 1.f);
}

// ---- exact-codegen MAC: one VOP2 each (R3/R9-proven)
#define FMAC(a, h, w) asm("v_fmac_f32 %0, %1, %2" : "+v"(a) : "v"(h), "v"(w))
#define VMUL(a, h, w) asm("v_mul_f32 %0, %1, %2" : "=v"(a) : "v"(h), "v"(w))
#define MAC4(hc, wa, wb, wcc, wd) \
    FMAC(s0, hc, wa); FMAC(s1, hc, wb); FMAC(s2, hc, wcc); FMAC(s3, hc, wd)

// ---- fused DPP butterfly reduce (R3/R9-proven)
#define RED_STAGE(ctrl) \
    "v_add_f32_dpp %0, %0, %0 " ctrl " row_mask:0xf bank_mask:0xf\n\t" \
    "v_add_f32_dpp %1, %1, %1 " ctrl " row_mask:0xf bank_mask:0xf\n\t" \
    "v_add_f32_dpp %2, %2, %2 " ctrl " row_mask:0xf bank_mask:0xf\n\t" \
    "v_add_f32_dpp %3, %3, %3 " ctrl " row_mask:0xf bank_mask:0xf\n\t"
#define REDUCE_L1 asm("s_nop 1\n\t" \
    RED_STAGE("quad_perm:[1,0,3,2]") \
    RED_STAGE("quad_perm:[2,3,0,1]") \
    RED_STAGE("row_half_mirror") \
    : "+v"(s0), "+v"(s1), "+v"(s2), "+v"(s3))
#define REDUCE_L2 asm("s_nop 1\n\t" \
    RED_STAGE("quad_perm:[1,0,3,2]") \
    RED_STAGE("quad_perm:[2,3,0,1]") \
    RED_STAGE("row_half_mirror") \
    RED_STAGE("row_mirror") \
    : "+v"(s0), "+v"(s1), "+v"(s2), "+v"(s3))

// ---- weights pinned to ARCH VGPRs v40..v103 (named-register homes; kills the
// AGPR park + per-use v_accvgpr_read tax: gfx9 VALU src encoding has no AGPR space)
#define DECLW \
    register float K0  asm("v40");  register float K1  asm("v41");  \
    register float K2  asm("v42");  register float K3  asm("v43");  \
    register float K4  asm("v44");  register float K5  asm("v45");  \
    register float K6  asm("v46");  register float K7  asm("v47");  \
    register float K8  asm("v48");  register float K9  asm("v49");  \
    register float K10 asm("v50");  register float K11 asm("v51");  \
    register float K12 asm("v52");  register float K13 asm("v53");  \
    register float K14 asm("v54");  register float K15 asm("v55");  \
    register float K16 asm("v56");  register float K17 asm("v57");  \
    register float K18 asm("v58");  register float K19 asm("v59");  \
    register float K20 asm("v60");  register float K21 asm("v61");  \
    register float K22 asm("v62");  register float K23 asm("v63");  \
    register float K24 asm("v64");  register float K25 asm("v65");  \
    register float K26 asm("v66");  register float K27 asm("v67");  \
    register float K28 asm("v68");  register float K29 asm("v69");  \
    register float K30 asm("v70");  register float K31 asm("v71");  \
    register float K32 asm("v72");  register float K33 asm("v73");  \
    register float K34 asm("v74");  register float K35 asm("v75");  \
    register float K36 asm("v76");  register float K37 asm("v77");  \
    register float K38 asm("v78");  register float K39 asm("v79");  \
    register float K40 asm("v80");  register float K41 asm("v81");  \
    register float K42 asm("v82");  register float K43 asm("v83");  \
    register float K44 asm("v84");  register float K45 asm("v85");  \
    register float K46 asm("v86");  register float K47 asm("v87");  \
    register float K48 asm("v88");  register float K49 asm("v89");  \
    register float K50 asm("v90");  register float K51 asm("v91");  \
    register float K52 asm("v92");  register float K53 asm("v93");  \
    register float K54 asm("v94");  register float K55 asm("v95");  \
    register float K56 asm("v96");  register float K57 asm("v97");  \
    register float K58 asm("v98");  register float K59 asm("v99");  \
    register float K60 asm("v100"); register float K61 asm("v101"); \
    register float K62 asm("v102"); register float K63 asm("v103");

#define LOADW4(d0, d1, d2, d3, src) { float4 _t = (src); d0 = _t.x; d1 = _t.y; d2 = _t.z; d3 = _t.w; }

// 64 MACs, K(ki), K(16+ki), K(32+ki), K(48+ki) per h element ki (R9-exact order)
#define MACALL \
    VMUL(s0, hv0.x, K0);  VMUL(s1, hv0.x, K16); VMUL(s2, hv0.x, K32); VMUL(s3, hv0.x, K48); \
    MAC4(hv0.y, K1,  K17, K33, K49); \
    MAC4(hv0.z, K2,  K18, K34, K50); \
    MAC4(hv0.w, K3,  K19, K35, K51); \
    MAC4(hv1.x, K4,  K20, K36, K52); \
    MAC4(hv1.y, K5,  K21, K37, K53); \
    MAC4(hv1.z, K6,  K22, K38, K54); \
    MAC4(hv1.w, K7,  K23, K39, K55); \
    MAC4(hv2.x, K8,  K24, K40, K56); \
    MAC4(hv2.y, K9,  K25, K41, K57); \
    MAC4(hv2.z, K10, K26, K42, K58); \
    MAC4(hv2.w, K11, K27, K43, K59); \
    MAC4(hv3.x, K12, K28, K44, K60); \
    MAC4(hv3.y, K13, K29, K45, K61); \
    MAC4(hv3.z, K14, K30, K46, K62); \
    MAC4(hv3.w, K15, K31, K47, K63);

// ---------------- kernel 1: W1E[v] = Wih1 @ emb[v] + bih1 + bhh1  (R9-proven)
__global__ __launch_bounds__(256)
__attribute__((amdgpu_waves_per_eu(1, 2)))
void k_w1e(
    const float* __restrict__ emb, const float* __restrict__ Wih1,
    const float* __restrict__ bih1, const float* __restrict__ bhh1,
    float* __restrict__ W1E)
{
    __shared__ float sA[32][128];
    __shared__ float sW[32][132];
    const int tid = threadIdx.x;
    const int base = blockIdx.x * 128;
    const int tx = tid & 15, ty = tid >> 4;
    const int ox = tx * 8, py = ty * 8;
    const int pl = tid & 127, half = tid >> 7;
    const int rv = min(base + pl, VOCAB - 1);   // clamped read row (tail block)
    float acc[8][8];
#pragma unroll
    for (int p = 0; p < 8; ++p)
#pragma unroll
        for (int o = 0; o < 8; ++o) acc[p][o] = 0.f;
    const float4* ws = (const float4*)(Wih1 + (size_t)pl * EMB + half * 16);
    const float4* as = (const float4*)(emb + (size_t)rv * EMB + half * 16);
    float4 qw[2][4], qe[2][4];
#pragma unroll
    for (int kc = 0; kc < 2; ++kc)
#pragma unroll
        for (int k = 0; k < 4; ++k) {
            qw[kc][k] = ws[kc * 8 + k];
            qe[kc][k] = as[kc * 8 + k];
        }
    for (int kc = 0; kc < 2; ++kc) {
        {
            const int jb = half * 16;
#pragma unroll
            for (int k = 0; k < 4; ++k) {
                float4 q = qw[kc][k], e = qe[kc][k];
                sW[jb + 4*k + 0][pl] = q.x; sW[jb + 4*k + 1][pl] = q.y;
                sW[jb + 4*k + 2][pl] = q.z; sW[jb + 4*k + 3][pl] = q.w;
                sA[jb + 4*k + 0][pl] = e.x; sA[jb + 4*k + 1][pl] = e.y;
                sA[jb + 4*k + 2][pl] = e.z; sA[jb + 4*k + 3][pl] = e.w;
            }
        }
        __syncthreads();
#pragma unroll 4
        for (int j = 0; j < 32; ++j) {
            float4 a0 = *(const float4*)&sA[j][py];
            float4 a1 = *(const float4*)&sA[j][py + 4];
            float4 b0 = *(const float4*)&sW[j][ox];
            float4 b1 = *(const float4*)&sW[j][ox + 4];
            float av[8] = {a0.x,a0.y,a0.z,a0.w,a1.x,a1.y,a1.z,a1.w};
            float bv[8] = {b0.x,b0.y,b0.z,b0.w,b1.x,b1.y,b1.z,b1.w};
#pragma unroll
            for (int p = 0; p < 8; ++p)
#pragma unroll
                for (int o = 0; o < 8; ++o)
                    acc[p][o] = fmaf(av[p], bv[o], acc[p][o]);
        }
        __syncthreads();
    }
    float bo[8];
#pragma unroll
    for (int o = 0; o < 8; ++o) bo[o] = bih1[ox + o] + bhh1[ox + o];
#pragma unroll
    for (int p = 0; p < 8; ++p) {
        const int vout = base + py + p;
        if (vout < VOCAB) {
            float* cp = W1E + (size_t)vout * HID + ox;
            *(float4*)cp       = make_float4(acc[p][0]+bo[0], acc[p][1]+bo[1], acc[p][2]+bo[2], acc[p][3]+bo[3]);
            *(float4*)(cp + 4) = make_float4(acc[p][4]+bo[4], acc[p][5]+bo[5], acc[p][6]+bo[6], acc[p][7]+bo[7]);
        }
    }
}

// block-wide sum for 768 threads (12 waves); pass 0 from non-contributing lanes
__device__ inline float bsum768(float v, volatile float* sc, int tid) {
#pragma unroll
    for (int off = 32; off > 0; off >>= 1) v += __shfl_down(v, off, 64);
    __syncthreads();
    if ((tid & 63) == 0) sc[tid >> 6] = v;
    __syncthreads();
    float s = 0.f;
#pragma unroll
    for (int k = 0; k < 12; ++k) s += sc[k];
    return s;
}

// step body as a MACRO (no lambda: register vars cannot be captured by reference)
#define DO_STEP(t, pslot, tn, rp, wpt) do { \
    const float pv_ = pslot; \
    float4 hv0 = (rp)[0], hv1 = (rp)[1], hv2 = (rp)[2], hv3 = (rp)[3]; \
    float s0, s1, s2, s3; \
    MACALL \
    if (L1) { REDUCE_L1; } else { REDUCE_L2; } \
    if (pfe) pslot = W1E[(size_t)tok[tn] * HID + wrow];   /* prefetch 2 ahead */ \
    if (wr_en) { \
        float ta_ = (e & 1) ? s1 : s0; \
        float tb_ = (e & 1) ? s3 : s2; \
        float v_  = (e & 2) ? tb_ : ta_; \
        if (L1) *(wpt) = fast_tanh(pv_ + v_); \
        else    *(wpt) = ((t) > 0) ? fast_tanh(b2w + v_) : 0.f;   /* h2_{-1}=0 */ \
    } \
    __syncthreads(); \
} while (0)

// ---------------- kernel 2: fused two-layer recurrence — R9-champion structure,
// weights pinned to arch VGPRs v40..v103 (round-10 change; math identical).
// waves 0-3 (L1): h1_t = tanh(W1E[tok[t]][r] + Whh1 @ h1_{t-1})
// waves 4-11(L2): h2_{t-1} = tanh(b2 + Wih2@h1_{t-1} + Whh2@h2_{t-2})  (lag-1)
__global__ __launch_bounds__(768)
__attribute__((amdgpu_waves_per_eu(3, 3)))
void k_rnn_fused(
    const int* __restrict__ x, const float* __restrict__ W1E,
    const float* __restrict__ Whh1,
    const float* __restrict__ Wih2, const float* __restrict__ bih2,
    const float* __restrict__ bhh2, const float* __restrict__ Whh2,
    const float* __restrict__ ln_g, const float* __restrict__ ln_b,
    const float* __restrict__ projW, const float* __restrict__ proj_b,
    const float* __restrict__ on_g, const float* __restrict__ on_b,
    float* __restrict__ out)
{
    // h layout: value i at word (i>>4)*20 + (i&15) -> conflict-free ds_read_b128.
    __shared__ __align__(16) float h1[2][160];
    __shared__ __align__(16) float h2[2][160];
    __shared__ int   tok[512];
    __shared__ float sfin[HID];
    __shared__ float xn[HID];
    __shared__ float sc[12];

    const int bb   = blockIdx.x;
    const int tid  = threadIdx.x;
    const int w    = tid >> 6;
    const int lane = tid & 63;
    const bool L1  = (w < 4);
    const int  e   = lane & 7;                     // column-eighth
    const int  m   = L1 ? 0 : ((lane >> 3) & 1);   // L2: 0 = Wih2 (h1), 1 = Whh2 (h2)
    const int  rg  = L1 ? (lane >> 3) : (lane >> 4);
    const int  rowbase = L1 ? (32 * w + rg) : (16 * (w - 4) + rg);
    const int  rstep   = L1 ? 8 : 4;
    const float* wmat  = L1 ? Whh1 : (m ? Whh2 : Wih2);

    // ---- 4 rows x 16 cols of weights, pinned in v40..v103
    DECLW
    const float4* wr0 = (const float4*)(wmat + (size_t)(rowbase            ) * HID + e * 16);
    const float4* wr1 = (const float4*)(wmat + (size_t)(rowbase +     rstep) * HID + e * 16);
    const float4* wr2 = (const float4*)(wmat + (size_t)(rowbase + 2 * rstep) * HID + e * 16);
    const float4* wr3 = (const float4*)(wmat + (size_t)(rowbase + 3 * rstep) * HID + e * 16);
    LOADW4(K0,  K1,  K2,  K3,  wr0[0]); LOADW4(K4,  K5,  K6,  K7,  wr0[1]);
    LOADW4(K8,  K9,  K10, K11, wr0[2]); LOADW4(K12, K13, K14, K15, wr0[3]);
    LOADW4(K16, K17, K18, K19, wr1[0]); LOADW4(K20, K21, K22, K23, wr1[1]);
    LOADW4(K24, K25, K26, K27, wr1[2]); LOADW4(K28, K29, K30, K31, wr1[3]);
    LOADW4(K32, K33, K34, K35, wr2[0]); LOADW4(K36, K37, K38, K39, wr2[1]);
    LOADW4(K40, K41, K42, K43, wr2[2]); LOADW4(K44, K45, K46, K47, wr2[3]);
    LOADW4(K48, K49, K50, K51, wr3[0]); LOADW4(K52, K53, K54, K55, wr3[1]);
    LOADW4(K56, K57, K58, K59, wr3[2]); LOADW4(K60, K61, K62, K63, wr3[3]);

    // publisher role: lanes e<4 (for L2 only m==0 half) write row rowbase+(e&3)*rstep
    const bool wr_en = L1 ? (e < 4) : (m == 0 && e < 4);
    const int  wrow  = rowbase + (e & 3) * rstep;
    const int  wword = ((wrow >> 4) * 20) + (wrow & 15);
    const float b2w  = (!L1 && wr_en) ? (bih2[wrow] + bhh2[wrow]) : 0.f;
    const bool pfe   = L1 && wr_en;                // this lane gathers pre values

    if (tid < 160) { h1[0][tid] = 0.f; h2[0][tid] = 0.f; }
    if (tid < 512) tok[tid] = x[bb * 512 + tid];

    // parity-resolved pointers (even t reads [0] writes [1]; odd t flips)
    const float* srcb = (L1 || m == 0) ? &h1[0][0] : &h2[0][0];
    const float4* rp0 = (const float4*)(srcb + e * 20);
    const float4* rp1 = (const float4*)(srcb + 160 + e * 20);
    float* dstb = L1 ? &h1[0][0] : &h2[0][0];
    float* wp_e = dstb + 160 + wword;   // even step writes parity 1
    float* wp_o = dstb + wword;         // odd step writes parity 0

    __syncthreads();                    // h init + tok visible

    // pre-value register ring (2-step prefetch): pA even steps, pB odd steps
    float pA = 0.f, pB = 0.f;
    if (pfe) {
        pA = W1E[(size_t)tok[0] * HID + wrow];
        pB = W1E[(size_t)tok[1] * HID + wrow];
    }

#pragma unroll 1
    for (int t = 0; t < 512; t += 2) {
        DO_STEP(t,     pA, (t + 2 < 512) ? t + 2 : 511, rp0, wp_e);
        DO_STEP(t + 1, pB, (t + 3 < 512) ? t + 3 : 511, rp1, wp_o);
    }

    // drain: h2_511 = tanh(b2 + Wih2@h1_511 + Whh2@h2_510); both live at parity 0.
    // L1 lanes compute a dead value into h1[1] (harmless).
    {
        float* wpD = L1 ? wp_e : &sfin[wrow];
        DO_STEP(512, pA, 511, rp0, wpD);
    }

    // ---- epilogue: LN -> proj+tanh -> LN (R3/R9-proven)
    const int i = tid & 127;
    float hn = (tid < 128) ? sfin[i] : 0.f;
    float s1v = bsum768(hn, sc, tid);
    float s2v = bsum768(hn * hn, sc, tid);
    float mu = s1v * (1.f / 128.f);
    float var = s2v * (1.f / 128.f) - mu * mu;
    __syncthreads();
    if (tid < 128) xn[i] = (hn - mu) * rsqrtf(var + 1e-5f) * ln_g[i] + ln_b[i];
    __syncthreads();
    float pv = 0.f;
    if (tid < 128) {
        float a0 = proj_b[i], a1 = 0, a2 = 0, a3 = 0;
        const float4* hp = (const float4*)xn;
        const float4* pr = (const float4*)(projW + (size_t)i * HID);
#pragma unroll
        for (int k = 0; k < HID / 4; ++k) {
            float4 u = pr[k];
            float4 hv = hp[k];
            a0 = fmaf(hv.x, u.x, a0); a1 = fmaf(hv.y, u.y, a1);
            a2 = fmaf(hv.z, u.z, a2); a3 = fmaf(hv.w, u.w, a3);
        }
        pv = tanhf((a0 + a1) + (a2 + a3));
    }
    float t1 = bsum768(pv, sc, tid);
    float t2 = bsum768(pv * pv, sc, tid);
    float mu2 = t1 * (1.f / 128.f);
    float var2 = t2 * (1.f / 128.f) - mu2 * mu2;
    if (tid < 128)
        out[(size_t)bb * HID + i] = (pv - mu2) * rsqrtf(var2 + 1e-5f) * on_g[i] + on_b[i];
}

extern "C" void kernel_launch(void* const* d_in, const int* in_sizes, int n_in,
                              void* d_out, int out_size, void* d_ws, size_t ws_size,
                              hipStream_t stream)
{
    const int*   x     = (const int*)  d_in[0];
    const float* emb   = (const float*)d_in[1];
    const float* Wih1  = (const float*)d_in[2];
    const float* bih1  = (const float*)d_in[3];
    const float* Whh1  = (const float*)d_in[4];
    const float* bhh1  = (const float*)d_in[5];
    const float* Wih2  = (const float*)d_in[6];
    const float* bih2  = (const float*)d_in[7];
    const float* Whh2  = (const float*)d_in[8];
    const float* bhh2  = (const float*)d_in[9];
    const float* ln_g  = (const float*)d_in[10];
    const float* ln_b  = (const float*)d_in[11];
    const float* projW = (const float*)d_in[12];
    const float* projb = (const float*)d_in[13];
    const float* on_g  = (const float*)d_in[14];
    const float* on_b  = (const float*)d_in[15];

    float* W1E = (float*)d_ws;   // [VOCAB][128] fp32 = 61.4 MB (ws is 64 MiB)

    k_w1e<<<(VOCAB + 127) / 128, 256, 0, stream>>>(emb, Wih1, bih1, bhh1, W1E);
    k_rnn_fused<<<256, 768, 0, stream>>>(x, W1E, Whh1, Wih2, bih2, bhh2, Whh2,
                                         ln_g, ln_b, projW, projb, on_g, on_b,
                                         (float*)d_out);
}